// Round 15
// baseline (1408.278 us; speedup 1.0000x reference)
//
#include <hip/hip_runtime.h>
#include <stdint.h>

// Problem constants
#define RR 2048
#define NND 53
#define DD 512
#define CCC 51
#define MM (RR*NND)          // 108544
#define MHALF 54272
#define KCLS (NND*DD)        // 27136
#define MAGIC53 1296593901ULL // ceil(2^36/53); valid for m < 4e9

using u16 = unsigned short;
using u32 = unsigned int;
using f32x4 = __attribute__((ext_vector_type(4))) float;
using s16x8 = __attribute__((ext_vector_type(8))) short;

static __device__ __forceinline__ u16 f2b(float f) {
  u32 x = __float_as_uint(f);
  x += 0x7FFFu + ((x >> 16) & 1u);
  return (u16)(x >> 16);
}
static __device__ __forceinline__ float b2f(u16 u) {
  return __uint_as_float(((u32)u) << 16);
}
static __device__ __forceinline__ float fsigm(float x) {
  return __builtin_amdgcn_rcpf(1.f + __builtin_amdgcn_exp2f(-1.442695041f * x));
}
static __device__ __forceinline__ float ftanh(float x) {
  return 1.f - 2.f * __builtin_amdgcn_rcpf(1.f + __builtin_amdgcn_exp2f(2.885390082f * x));
}

// ---------------- prep kernels ----------------

__global__ void k_cvt4(const float* __restrict__ src, u16* __restrict__ dst, int n4) {
  int i = blockIdx.x * 256 + threadIdx.x;
  if (i >= n4) return;
  float4 v = *reinterpret_cast<const float4*>(src + (size_t)i * 4);
  uint2 o;
  o.x = (u32)f2b(v.x) | ((u32)f2b(v.y) << 16);
  o.y = (u32)f2b(v.z) | ((u32)f2b(v.w) << 16);
  *reinterpret_cast<uint2*>(dst + (size_t)i * 4) = o;
}

__global__ void k_wcat(const float* __restrict__ w3w, const float* __restrict__ w4w,
                       const float* __restrict__ w5w, u16* __restrict__ Wcat) {
  int idx = blockIdx.x * 256 + threadIdx.x;
  if (idx >= 1536 * 512) return;
  int j = idx >> 9, k = idx & 511;
  const float* w = (j < 512) ? w3w : (j < 1024) ? w4w : w5w;
  int jj = j & 511;
  float v = w[(size_t)jj * 1024 + k] + w[(size_t)jj * 1024 + 512 + k];
  Wcat[idx] = f2b(v);
}

__global__ void k_wcls(const float* __restrict__ wcls, u16* __restrict__ dst) {
  int cc = blockIdx.x; // 0..63
  for (int t = threadIdx.x; t < KCLS; t += 256)
    dst[(size_t)cc * KCLS + t] = (cc < CCC) ? f2b(wcls[(size_t)cc * KCLS + t]) : (u16)0;
}

__global__ void k_gatherB(const int* __restrict__ so, const float* __restrict__ matrix,
                          float* __restrict__ Bmat) {
  int r = blockIdx.x;
  int c = threadIdx.x;
  if (c < CCC) {
    int s = so[2 * r], o = so[2 * r + 1];
    Bmat[r * CCC + c] = matrix[((size_t)s * 151 + o) * CCC + c];
  }
}

__global__ void k_bias(const float* __restrict__ b3w, const float* __restrict__ b3u,
                       const float* __restrict__ b4w, const float* __restrict__ b5w,
                       const float* __restrict__ b5u, float* __restrict__ bias) {
  int j = blockIdx.x * 256 + threadIdx.x;
  if (j >= 512) return;
  bias[j]        = b3w[j] + b3u[j];
  bias[512 + j]  = b4w[j] + b3u[j];
  bias[1024 + j] = b5w[j] + b5u[j];
}

// ---------------- per-step kernels ----------------

// t=0 fused: inp f32 -> hb bf16 (full copy) + ar reduction in the same pass
__global__ __launch_bounds__(256) void k_redcvt(const float* __restrict__ inp,
                                                const float* __restrict__ Bmat,
                                                u16* __restrict__ hb,
                                                u16* __restrict__ ar) {
  __shared__ float Bs[CCC];
  int r = blockIdx.x, tid = threadIdx.x;
  if (tid < CCC) Bs[tid] = Bmat[r * CCC + tid];
  __syncthreads();
  int d0 = tid * 2;
  const float* irow = inp + (size_t)r * NND * DD;
  u16* hrow = hb + (size_t)r * NND * DD;
  float a0 = 0.f, a1 = 0.f, h0 = 0.f, h1 = 0.f;
  for (int i = 0; i < NND; ++i) {
    float2 v = *reinterpret_cast<const float2*>(irow + (size_t)i * DD + d0);
    *reinterpret_cast<u32*>(hrow + (size_t)i * DD + d0) =
        (u32)f2b(v.x) | ((u32)f2b(v.y) << 16);
    if (i < 2) { h0 += v.x; h1 += v.y; }
    else       { float s = Bs[i - 2]; a0 += s * v.x; a1 += s * v.y; }
  }
  *reinterpret_cast<u32*>(ar + (size_t)(2 * r) * DD + d0) =
      (u32)f2b(a0) | ((u32)f2b(a1) << 16);
  *reinterpret_cast<u32*>(ar + (size_t)(2 * r + 1) * DD + d0) =
      (u32)f2b(h0) | ((u32)f2b(h1) << 16);
}

__global__ __launch_bounds__(256) void k_reduce(const u16* __restrict__ hb,
                                                const float* __restrict__ Bmat,
                                                u16* __restrict__ ar) {
  __shared__ float Bs[CCC];
  int r = blockIdx.x, tid = threadIdx.x;
  if (tid < CCC) Bs[tid] = Bmat[r * CCC + tid];
  __syncthreads();
  int d0 = tid * 2;
  const u16* hrow = hb + (size_t)r * NND * DD;
  float a0 = 0.f, a1 = 0.f;
  for (int c = 0; c < CCC; ++c) {
    u32 v = *reinterpret_cast<const u32*>(hrow + (size_t)(2 + c) * DD + d0);
    float s = Bs[c];
    a0 += s * b2f((u16)v);
    a1 += s * b2f((u16)(v >> 16));
  }
  u32 v0 = *reinterpret_cast<const u32*>(hrow + 0 * DD + d0);
  u32 v1 = *reinterpret_cast<const u32*>(hrow + 1 * DD + d0);
  float h0 = b2f((u16)v0) + b2f((u16)v1);
  float h1 = b2f((u16)(v0 >> 16)) + b2f((u16)(v1 >> 16));
  *reinterpret_cast<u32*>(ar + (size_t)(2 * r) * DD + d0) =
      (u32)f2b(a0) | ((u32)f2b(a1) << 16);
  *reinterpret_cast<u32*>(ar + (size_t)(2 * r + 1) * DD + d0) =
      (u32)f2b(h0) | ((u32)f2b(h1) << 16);
}

__global__ __launch_bounds__(256) void k_agemm(const u16* __restrict__ ar,
                                               const u16* __restrict__ Wcat,
                                               u16* __restrict__ gb) {
  const int tid = threadIdx.x, wid = tid >> 6, lane = tid & 63;
  const int m0 = blockIdx.x * 64 + wid * 16;
  const int n0 = blockIdx.y * 64;
  const int arow = lane & 15, kc = lane >> 4;
  f32x4 acc[4];
#pragma unroll
  for (int ni = 0; ni < 4; ++ni) acc[ni] = (f32x4){0.f, 0.f, 0.f, 0.f};
  const u16* ap = ar + (size_t)(m0 + arow) * DD;
#pragma unroll 2
  for (int kb = 0; kb < 16; ++kb) {
    const int k = kb * 32 + kc * 8;
    s16x8 aF = *reinterpret_cast<const s16x8*>(ap + k);
#pragma unroll
    for (int ni = 0; ni < 4; ++ni) {
      s16x8 bF = *reinterpret_cast<const s16x8*>(Wcat + (size_t)(n0 + ni * 16 + arow) * DD + k);
      acc[ni] = __builtin_amdgcn_mfma_f32_16x16x32_bf16(aF, bF, acc[ni], 0, 0, 0);
    }
  }
#pragma unroll
  for (int ni = 0; ni < 4; ++ni)
#pragma unroll
    for (int q = 0; q < 4; ++q)
      gb[(size_t)(m0 + kc * 4 + q) * 1536 + n0 + ni * 16 + arow] = f2b(acc[ni][q]);
}

// ===== split-GEMM GRU: G1 = h@w3u^T + gate epilogue (z->u8 direct scatter) =====
// Swizzle generalized: cpx = gridDim.x/8 (works for 1696 and 3392 grids).
__global__ __launch_bounds__(512, 2) void k_g1(const u16* __restrict__ hb,
                                               const u16* __restrict__ w3ub,
                                               const u16* __restrict__ gb,
                                               const float* __restrict__ Bmat,
                                               const float* __restrict__ bias,
                                               u16* __restrict__ rvh,
                                               unsigned char* __restrict__ zb8,
                                               int mbase) {
  __shared__ unsigned char lds[49152]; // A[0,16K) | B[16K,32K) | gS[32K,48K)
  __shared__ float sRowS[128];
  __shared__ int   fRowS[128];
  const int tid = threadIdx.x, wid = tid >> 6, lane = tid & 63;
  const int cpx = (int)gridDim.x >> 3;
  const int wg = ((blockIdx.x & 7) * cpx + (blockIdx.x >> 3)); // XCD swizzle
  const int m0 = mbase + (wg >> 2) * 128;
  const int n0 = (wg & 3) * 128;
  const int r0 = (int)(((unsigned long long)m0 * MAGIC53) >> 36);

  {
    const uint4* gsrc = reinterpret_cast<const uint4*>(gb);
    uint4* gdst = reinterpret_cast<uint4*>(lds + 32768);
#pragma unroll
    for (int c = tid; c < 1024; c += 512) {
      int slot = c >> 7, within = c & 127;
      gdst[c] = gsrc[(size_t)(2 * r0 + slot) * 192 + within];
    }
  }
  if (tid < 128) {
    int mg = m0 + tid;
    int rr = (int)(((unsigned long long)mg * MAGIC53) >> 36);
    int ii = mg - rr * 53;
    bool useA = (ii < 2);
    sRowS[tid] = useA ? 1.0f : Bmat[rr * CCC + (ii - 2)];
    fRowS[tid] = ((rr - r0) << 1) | (useA ? 0 : 1);
  }

  const int arow = lane & 15, kc = lane >> 4;
  const int R = (wid >> 1) * 32, C = (wid & 1) * 64;
  const int lrow = lane >> 3, linrow = (lane & 7) * 16;
  const unsigned char* ab = (const unsigned char*)hb;
  const unsigned char* bb = (const unsigned char*)w3ub;

  f32x4 acc[2][4];
#pragma unroll
  for (int a = 0; a < 2; ++a)
#pragma unroll
    for (int b = 0; b < 4; ++b) acc[a][b] = (f32x4){0.f, 0.f, 0.f, 0.f};

  for (int ks = 0; ks < 8; ++ks) {
    __syncthreads();
#pragma unroll
    for (int r = 0; r < 2; ++r) {
      int rowA = (r * 8 + wid) * 8 + lrow;
      int inr0 = linrow ^ ((rowA & 7) << 4);
      __builtin_amdgcn_global_load_lds(
          (const unsigned int*)(ab + (size_t)(m0 + rowA) * 1024 + ks * 128 + inr0),
          (unsigned int*)(lds + (r * 8 + wid) * 1024 + lane * 16), 16, 0, 0);
      __builtin_amdgcn_global_load_lds(
          (const unsigned int*)(bb + (size_t)(n0 + rowA) * 1024 + ks * 128 + inr0),
          (unsigned int*)(lds + 16384 + (r * 8 + wid) * 1024 + lane * 16), 16, 0, 0);
    }
    __syncthreads();
#pragma unroll
    for (int ks2 = 0; ks2 < 2; ++ks2) {
      const int kb = kc * 16 + ks2 * 64;
      s16x8 aF[2], bF[4];
#pragma unroll
      for (int mi = 0; mi < 2; ++mi) {
        int row = R + mi * 16 + arow;
        aF[mi] = *reinterpret_cast<const s16x8*>(lds + row * 128 + (kb ^ ((row & 7) << 4)));
      }
#pragma unroll
      for (int ni = 0; ni < 4; ++ni) {
        int col = C + ni * 16 + arow;
        bF[ni] = *reinterpret_cast<const s16x8*>(lds + 16384 + col * 128 + (kb ^ ((col & 7) << 4)));
      }
#pragma unroll
      for (int mi = 0; mi < 2; ++mi)
#pragma unroll
        for (int ni = 0; ni < 4; ++ni)
          acc[mi][ni] = __builtin_amdgcn_mfma_f32_16x16x32_bf16(aF[mi], bF[ni], acc[mi][ni], 0, 0, 0);
    }
  }
  __syncthreads(); // K-loop done; A/B LDS reusable as output tile

  // stage h tile (coalesced, L2-hot) into output LDS region
  {
    const unsigned char* srcb = (const unsigned char*)(hb + (size_t)m0 * 512 + n0);
#pragma unroll
    for (int j = 0; j < 4; ++j) {
      int idx = tid + j * 512;
      int row = idx >> 4, incol = (idx & 15) * 16;
      uint4 v = *reinterpret_cast<const uint4*>(srcb + (size_t)row * 1024 + incol);
      *reinterpret_cast<uint4*>(lds + row * 256 + (incol ^ ((row & 7) << 4))) = v;
    }
  }
  __syncthreads();

  const u16* gS = (const u16*)(lds + 32768);
  float bz[4], br[4];
#pragma unroll
  for (int ni = 0; ni < 4; ++ni) {
    int colg = n0 + C + ni * 16 + arow;
    bz[ni] = bias[colg];
    br[ni] = bias[512 + colg];
  }

#pragma unroll
  for (int mi = 0; mi < 2; ++mi) {
#pragma unroll
    for (int q = 0; q < 4; ++q) {
      const int row = R + mi * 16 + kc * 4 + q;
      const float s = sRowS[row];
      const u16* gp = gS + fRowS[row] * 1024;
      unsigned char* zrow = zb8 + (size_t)(m0 - mbase + row) * 512 + n0;
#pragma unroll
      for (int ni = 0; ni < 4; ++ni) {
        const int cl = C + ni * 16 + arow;
        const int colg = n0 + cl;
        const float u3 = acc[mi][ni][q];
        const float zv = fsigm(s * b2f(gp[colg]) + u3 + bz[ni]);
        const float rv = fsigm(s * b2f(gp[512 + colg]) + u3 + br[ni]);
        u16* hp = reinterpret_cast<u16*>(lds + row * 256 + ((cl * 2) ^ ((row & 7) << 4)));
        const float hval = b2f(*hp);
        *hp = f2b(rv * hval); // owner RMW: read h, write rvh
        zrow[cl] = (unsigned char)fmaf(zv, 255.f, 0.5f); // direct scatter store
      }
    }
  }
  __syncthreads();
  {
    unsigned char* dstb = (unsigned char*)(rvh + (size_t)(m0 - mbase) * 512 + n0);
#pragma unroll
    for (int j = 0; j < 4; ++j) {
      int idx = tid + j * 512;
      int row = idx >> 4, incol = (idx & 15) * 16;
      uint4 v = *reinterpret_cast<const uint4*>(lds + row * 256 + (incol ^ ((row & 7) << 4)));
      *reinterpret_cast<uint4*>(dstb + (size_t)row * 1024 + incol) = v;
    }
  }
}

// ===== G2 = rvh@w5u^T + h_new epilogue (zT LDS-staged, 57KB) =====
__global__ __launch_bounds__(512, 2) void k_g2(u16* __restrict__ hb,
                                               const u16* __restrict__ w5ub,
                                               const u16* __restrict__ gb,
                                               const float* __restrict__ Bmat,
                                               const float* __restrict__ bias,
                                               const u16* __restrict__ rvh,
                                               const unsigned char* __restrict__ zb8,
                                               int mbase) {
  __shared__ unsigned char lds[57344]; // A[0,16K)|B[16K,32K)|gS[32K,40K)|zT[40K,56K)
  __shared__ float sRowS[128];
  __shared__ int   fRowS[128];
  const int tid = threadIdx.x, wid = tid >> 6, lane = tid & 63;
  const int cpx = (int)gridDim.x >> 3;
  const int wg = ((blockIdx.x & 7) * cpx + (blockIdx.x >> 3));
  const int m0 = mbase + (wg >> 2) * 128;
  const int n0 = (wg & 3) * 128;
  const int r0 = (int)(((unsigned long long)m0 * MAGIC53) >> 36);

  {
    const uint4* gsrc = reinterpret_cast<const uint4*>(gb);
    uint4* gdst = reinterpret_cast<uint4*>(lds + 32768);
    if (tid < 512) {
      int slot = tid >> 6, within = tid & 63;
      gdst[tid] = gsrc[(size_t)(2 * r0 + slot) * 192 + 128 + within];
    }
  }
  // stage z-u8 tile (coalesced)
  {
    const unsigned char* zsrc = zb8 + (size_t)(m0 - mbase) * 512 + n0;
#pragma unroll
    for (int j = 0; j < 2; ++j) {
      int idx = tid + j * 512;
      int row = idx >> 3, incol = (idx & 7) * 16;
      uint4 v = *reinterpret_cast<const uint4*>(zsrc + (size_t)row * 512 + incol);
      *reinterpret_cast<uint4*>(lds + 40960 + row * 128 + incol) = v;
    }
  }
  if (tid < 128) {
    int mg = m0 + tid;
    int rr = (int)(((unsigned long long)mg * MAGIC53) >> 36);
    int ii = mg - rr * 53;
    bool useA = (ii < 2);
    sRowS[tid] = useA ? 1.0f : Bmat[rr * CCC + (ii - 2)];
    fRowS[tid] = ((rr - r0) << 1) | (useA ? 0 : 1);
  }

  const int arow = lane & 15, kc = lane >> 4;
  const int R = (wid >> 1) * 32, C = (wid & 1) * 64;
  const int lrow = lane >> 3, linrow = (lane & 7) * 16;
  const unsigned char* ab = (const unsigned char*)rvh;
  const unsigned char* bb = (const unsigned char*)w5ub;

  f32x4 acc[2][4];
#pragma unroll
  for (int a = 0; a < 2; ++a)
#pragma unroll
    for (int b = 0; b < 4; ++b) acc[a][b] = (f32x4){0.f, 0.f, 0.f, 0.f};

  for (int ks = 0; ks < 8; ++ks) {
    __syncthreads();
#pragma unroll
    for (int r = 0; r < 2; ++r) {
      int rowA = (r * 8 + wid) * 8 + lrow;
      int inr0 = linrow ^ ((rowA & 7) << 4);
      __builtin_amdgcn_global_load_lds(
          (const unsigned int*)(ab + (size_t)(m0 - mbase + rowA) * 1024 + ks * 128 + inr0),
          (unsigned int*)(lds + (r * 8 + wid) * 1024 + lane * 16), 16, 0, 0);
      __builtin_amdgcn_global_load_lds(
          (const unsigned int*)(bb + (size_t)(n0 + rowA) * 1024 + ks * 128 + inr0),
          (unsigned int*)(lds + 16384 + (r * 8 + wid) * 1024 + lane * 16), 16, 0, 0);
    }
    __syncthreads();
#pragma unroll
    for (int ks2 = 0; ks2 < 2; ++ks2) {
      const int kb = kc * 16 + ks2 * 64;
      s16x8 aF[2], bF[4];
#pragma unroll
      for (int mi = 0; mi < 2; ++mi) {
        int row = R + mi * 16 + arow;
        aF[mi] = *reinterpret_cast<const s16x8*>(lds + row * 128 + (kb ^ ((row & 7) << 4)));
      }
#pragma unroll
      for (int ni = 0; ni < 4; ++ni) {
        int col = C + ni * 16 + arow;
        bF[ni] = *reinterpret_cast<const s16x8*>(lds + 16384 + col * 128 + (kb ^ ((col & 7) << 4)));
      }
#pragma unroll
      for (int mi = 0; mi < 2; ++mi)
#pragma unroll
        for (int ni = 0; ni < 4; ++ni)
          acc[mi][ni] = __builtin_amdgcn_mfma_f32_16x16x32_bf16(aF[mi], bF[ni], acc[mi][ni], 0, 0, 0);
    }
  }
  __syncthreads();

  // stage h_old tile (coalesced) into output LDS region
  {
    const unsigned char* srcb = (const unsigned char*)(hb + (size_t)m0 * 512 + n0);
#pragma unroll
    for (int j = 0; j < 4; ++j) {
      int idx = tid + j * 512;
      int row = idx >> 4, incol = (idx & 15) * 16;
      uint4 v = *reinterpret_cast<const uint4*>(srcb + (size_t)row * 1024 + incol);
      *reinterpret_cast<uint4*>(lds + row * 256 + (incol ^ ((row & 7) << 4))) = v;
    }
  }
  __syncthreads();

  const u16* gS = (const u16*)(lds + 32768);
  const unsigned char* zT = lds + 40960;
  float bh[4];
#pragma unroll
  for (int ni = 0; ni < 4; ++ni) bh[ni] = bias[1024 + n0 + C + ni * 16 + arow];

#pragma unroll
  for (int mi = 0; mi < 2; ++mi) {
#pragma unroll
    for (int q = 0; q < 4; ++q) {
      const int row = R + mi * 16 + kc * 4 + q;
      const float s = sRowS[row];
      const u16* gp = gS + fRowS[row] * 512;
#pragma unroll
      for (int ni = 0; ni < 4; ++ni) {
        const int cl = C + ni * 16 + arow;
        const int colg = n0 + cl;
        const float hv = ftanh(acc[mi][ni][q] + s * b2f(gp[colg]) + bh[ni]);
        const float zv = (float)zT[row * 128 + cl] * (1.f / 255.f);
        u16* hp = reinterpret_cast<u16*>(lds + row * 256 + ((cl * 2) ^ ((row & 7) << 4)));
        const float ho = b2f(*hp);
        *hp = f2b(fmaf(zv, hv - ho, ho)); // owner RMW
      }
    }
  }
  __syncthreads();
  {
    unsigned char* dstb = (unsigned char*)(hb + (size_t)m0 * 512 + n0);
#pragma unroll
    for (int j = 0; j < 4; ++j) {
      int idx = tid + j * 512;
      int row = idx >> 4, incol = (idx & 15) * 16;
      uint4 v = *reinterpret_cast<const uint4*>(lds + row * 256 + (incol ^ ((row & 7) << 4)));
      *reinterpret_cast<uint4*>(dstb + (size_t)row * 1024 + incol) = v;
    }
  }
}

// ===== k_out2: out = relu([hf | inp] @ wout^T + bout) -> outb =====
__global__ __launch_bounds__(512, 2) void k_out2(const u16* __restrict__ hb,
                                                 const float* __restrict__ inp,
                                                 const u16* __restrict__ woutb,
                                                 const float* __restrict__ bout,
                                                 u16* __restrict__ outb) {
  __shared__ unsigned char lds[32768]; // A[0,16K) | B[16K,32K); reused as out tile
  const int tid = threadIdx.x, wid = tid >> 6, lane = tid & 63;
  const int wg = ((blockIdx.x & 7) * 424 + (blockIdx.x >> 3)); // 3392 = 8*424
  const int m0 = (wg >> 2) * 128;
  const int n0 = (wg & 3) * 128;

  const int arow = lane & 15, kc = lane >> 4;
  const int R = (wid >> 1) * 32, C = (wid & 1) * 64;
  const int lrow = lane >> 3, linrow = (lane & 7) * 16;
  const unsigned char* ab = (const unsigned char*)hb;
  const unsigned char* bb = (const unsigned char*)woutb; // row stride 2048 B (K=1024)

  f32x4 acc[2][4];
#pragma unroll
  for (int a = 0; a < 2; ++a)
#pragma unroll
    for (int b = 0; b < 4; ++b) acc[a][b] = (f32x4){0.f, 0.f, 0.f, 0.f};

  for (int ks = 0; ks < 16; ++ks) {
    __syncthreads();
#pragma unroll
    for (int r = 0; r < 2; ++r) {
      int rowA = (r * 8 + wid) * 8 + lrow;
      int inr0 = linrow ^ ((rowA & 7) << 4);
      if (ks < 8) {
        __builtin_amdgcn_global_load_lds(
            (const unsigned int*)(ab + (size_t)(m0 + rowA) * 1024 + ks * 128 + inr0),
            (unsigned int*)(lds + (r * 8 + wid) * 1024 + lane * 16), 16, 0, 0);
      } else {
        const float* sp = inp + (size_t)(m0 + rowA) * 512 + (((ks - 8) * 128 + inr0) >> 1);
        float4 v0 = *reinterpret_cast<const float4*>(sp);
        float4 v1 = *reinterpret_cast<const float4*>(sp + 4);
        uint4 o;
        o.x = (u32)f2b(v0.x) | ((u32)f2b(v0.y) << 16);
        o.y = (u32)f2b(v0.z) | ((u32)f2b(v0.w) << 16);
        o.z = (u32)f2b(v1.x) | ((u32)f2b(v1.y) << 16);
        o.w = (u32)f2b(v1.z) | ((u32)f2b(v1.w) << 16);
        *reinterpret_cast<uint4*>(lds + (r * 8 + wid) * 1024 + lane * 16) = o;
      }
      __builtin_amdgcn_global_load_lds(
          (const unsigned int*)(bb + (size_t)(n0 + rowA) * 2048 + ks * 128 + inr0),
          (unsigned int*)(lds + 16384 + (r * 8 + wid) * 1024 + lane * 16), 16, 0, 0);
    }
    __syncthreads();
#pragma unroll
    for (int ks2 = 0; ks2 < 2; ++ks2) {
      const int kb = kc * 16 + ks2 * 64;
      s16x8 aF[2], bF[4];
#pragma unroll
      for (int mi = 0; mi < 2; ++mi) {
        int row = R + mi * 16 + arow;
        aF[mi] = *reinterpret_cast<const s16x8*>(lds + row * 128 + (kb ^ ((row & 7) << 4)));
      }
#pragma unroll
      for (int ni = 0; ni < 4; ++ni) {
        int col = C + ni * 16 + arow;
        bF[ni] = *reinterpret_cast<const s16x8*>(lds + 16384 + col * 128 + (kb ^ ((col & 7) << 4)));
      }
#pragma unroll
      for (int mi = 0; mi < 2; ++mi)
#pragma unroll
        for (int ni = 0; ni < 4; ++ni)
          acc[mi][ni] = __builtin_amdgcn_mfma_f32_16x16x32_bf16(aF[mi], bF[ni], acc[mi][ni], 0, 0, 0);
    }
  }
  __syncthreads();

  float bov[4];
#pragma unroll
  for (int ni = 0; ni < 4; ++ni) bov[ni] = bout[n0 + C + ni * 16 + arow];

#pragma unroll
  for (int mi = 0; mi < 2; ++mi)
#pragma unroll
    for (int q = 0; q < 4; ++q) {
      const int row = R + mi * 16 + kc * 4 + q;
#pragma unroll
      for (int ni = 0; ni < 4; ++ni) {
        const int cl = C + ni * 16 + arow;
        float v = fmaxf(acc[mi][ni][q] + bov[ni], 0.f);
        *reinterpret_cast<u16*>(lds + row * 256 + ((cl * 2) ^ ((row & 7) << 4))) = f2b(v);
      }
    }
  __syncthreads();
  {
    unsigned char* dstb = (unsigned char*)(outb + (size_t)m0 * 512 + n0);
#pragma unroll
    for (int j = 0; j < 4; ++j) {
      int idx = tid + j * 512;
      int row = idx >> 4, incol = (idx & 15) * 16;
      uint4 v = *reinterpret_cast<const uint4*>(lds + row * 256 + (incol ^ ((row & 7) << 4)));
      *reinterpret_cast<uint4*>(dstb + (size_t)row * 1024 + incol) = v;
    }
  }
}

// ===== fallback kernels (only used if ws too small; proven r5 path) =====
__global__ __launch_bounds__(512, 4) void k_gru(u16* __restrict__ hb,
                                                const u16* __restrict__ w3ub,
                                                const u16* __restrict__ w5ub,
                                                const u16* __restrict__ gb,
                                                const float* __restrict__ Bmat,
                                                const float* __restrict__ bias) {
  __shared__ unsigned char hA[32768];
  __shared__ unsigned char hR[32768];
  __shared__ u16 gS[4][1536];
  __shared__ float sRow[32];
  __shared__ int   fRow[32];

  const int tid = threadIdx.x;
  const int wid = tid >> 6;
  const int lane = tid & 63;
  const int bid = blockIdx.x;
  const int m0 = ((bid & 7) * 424 + (bid >> 3)) * 32;
  const int r0 = (int)(((unsigned long long)m0 * MAGIC53) >> 36);

  {
    const char* src = (const char*)(hb + (size_t)m0 * DD);
#pragma unroll
    for (int c = tid; c < 2048; c += 512) {
      int row = c >> 6;
      int off = (c & 63) << 4;
      uint4 v = *reinterpret_cast<const uint4*>(src + (row << 10) + off);
      *reinterpret_cast<uint4*>(&hA[(row << 10) + (off ^ ((row & 7) << 4))]) = v;
    }
  }
  {
    const uint4* gsrc = reinterpret_cast<const uint4*>(gb + (size_t)(2 * r0) * 1536);
    uint4* gdst = reinterpret_cast<uint4*>(&gS[0][0]);
#pragma unroll
    for (int c = tid; c < 768; c += 512) gdst[c] = gsrc[c];
  }
  if (tid < 32) {
    int mg = m0 + tid;
    int rr = (int)(((unsigned long long)mg * MAGIC53) >> 36);
    int ii = mg - rr * 53;
    bool useA = (ii < 2);
    sRow[tid] = useA ? 1.0f : Bmat[rr * CCC + (ii - 2)];
    fRow[tid] = ((rr - r0) << 1) | (useA ? 0 : 1);
  }
  __syncthreads();

  const int colbase = wid << 6;
  const int arow = lane & 15;
  const int kc = lane >> 4;

  float bzv[4], brv[4], bhv[4];
#pragma unroll
  for (int ni = 0; ni < 4; ++ni) {
    int col = colbase + ni * 16 + arow;
    bzv[ni] = bias[col];
    brv[ni] = bias[512 + col];
    bhv[ni] = bias[1024 + col];
  }

  f32x4 acc[2][4];
#pragma unroll
  for (int a = 0; a < 2; ++a)
#pragma unroll
    for (int b = 0; b < 4; ++b) acc[a][b] = (f32x4){0.f, 0.f, 0.f, 0.f};

  const u16* b1p[4];
#pragma unroll
  for (int ni = 0; ni < 4; ++ni)
    b1p[ni] = w3ub + (size_t)(colbase + ni * 16 + arow) * DD;

#pragma unroll 2
  for (int kb = 0; kb < 16; ++kb) {
    const int k = kb * 32 + kc * 8;
    s16x8 aF[2], bF[4];
#pragma unroll
    for (int mi = 0; mi < 2; ++mi) {
      int row = mi * 16 + arow;
      aF[mi] = *reinterpret_cast<const s16x8*>(&hA[(row << 10) + ((k * 2) ^ ((row & 7) << 4))]);
    }
#pragma unroll
    for (int ni = 0; ni < 4; ++ni)
      bF[ni] = *reinterpret_cast<const s16x8*>(b1p[ni] + k);
#pragma unroll
    for (int mi = 0; mi < 2; ++mi)
#pragma unroll
      for (int ni = 0; ni < 4; ++ni)
        acc[mi][ni] = __builtin_amdgcn_mfma_f32_16x16x32_bf16(aF[mi], bF[ni], acc[mi][ni], 0, 0, 0);
  }

  u32 zpk[2][4][2];
#pragma unroll
  for (int mi = 0; mi < 2; ++mi) {
#pragma unroll
    for (int q = 0; q < 4; ++q) {
      const int row = mi * 16 + kc * 4 + q;
      const float s = sRow[row];
      const u16* gp = &gS[0][0] + fRow[row] * 1536;
#pragma unroll
      for (int ni = 0; ni < 4; ++ni) {
        const int col = colbase + ni * 16 + arow;
        const float u3 = acc[mi][ni][q];
        const float t3 = s * b2f(gp[col]);
        const float t4 = s * b2f(gp[512 + col]);
        const float zv = fsigm(t3 + u3 + bzv[ni]);
        const float rv = fsigm(t4 + u3 + brv[ni]);
        const float hval = b2f(*reinterpret_cast<const u16*>(
            &hA[(row << 10) + ((col * 2) ^ ((row & 7) << 4))]));
        *reinterpret_cast<u16*>(&hR[(row << 10) + ((col * 2) ^ ((row & 7) << 4))]) =
            f2b(rv * hval);
        const u32 zb2 = f2b(zv);
        if (q == 0)      zpk[mi][ni][0] = zb2;
        else if (q == 1) zpk[mi][ni][0] |= zb2 << 16;
        else if (q == 2) zpk[mi][ni][1] = zb2;
        else             zpk[mi][ni][1] |= zb2 << 16;
      }
    }
  }
  __syncthreads();

#pragma unroll
  for (int a = 0; a < 2; ++a)
#pragma unroll
    for (int b = 0; b < 4; ++b) acc[a][b] = (f32x4){0.f, 0.f, 0.f, 0.f};
  const u16* b2p[4];
#pragma unroll
  for (int ni = 0; ni < 4; ++ni)
    b2p[ni] = w5ub + (size_t)(colbase + ni * 16 + arow) * DD;
#pragma unroll 2
  for (int kb = 0; kb < 16; ++kb) {
    const int k = kb * 32 + kc * 8;
    s16x8 aF[2], bF[4];
#pragma unroll
    for (int mi = 0; mi < 2; ++mi) {
      int row = mi * 16 + arow;
      aF[mi] = *reinterpret_cast<const s16x8*>(&hR[(row << 10) + ((k * 2) ^ ((row & 7) << 4))]);
    }
#pragma unroll
    for (int ni = 0; ni < 4; ++ni)
      bF[ni] = *reinterpret_cast<const s16x8*>(b2p[ni] + k);
#pragma unroll
    for (int mi = 0; mi < 2; ++mi)
#pragma unroll
      for (int ni = 0; ni < 4; ++ni)
        acc[mi][ni] = __builtin_amdgcn_mfma_f32_16x16x32_bf16(aF[mi], bF[ni], acc[mi][ni], 0, 0, 0);
  }
  __syncthreads();

#pragma unroll
  for (int mi = 0; mi < 2; ++mi) {
#pragma unroll
    for (int q = 0; q < 4; ++q) {
      const int row = mi * 16 + kc * 4 + q;
      const float s = sRow[row];
      const u16* gp = &gS[0][0] + fRow[row] * 1536;
#pragma unroll
      for (int ni = 0; ni < 4; ++ni) {
        const int col = colbase + ni * 16 + arow;
        const float g5 = s * b2f(gp[1024 + col]);
        const float hv = ftanh(acc[mi][ni][q] + g5 + bhv[ni]);
        const float zv = b2f((u16)(zpk[mi][ni][q >> 1] >> ((q & 1) * 16)));
        const float ho = b2f(*reinterpret_cast<const u16*>(
            &hA[(row << 10) + ((col * 2) ^ ((row & 7) << 4))]));
        const float hnew = fmaf(zv, hv - ho, ho);
        *reinterpret_cast<u16*>(&hR[(row << 10) + ((col * 2) ^ ((row & 7) << 4))]) = f2b(hnew);
      }
    }
  }
  __syncthreads();
  {
    char* dst = (char*)(hb + (size_t)m0 * DD);
#pragma unroll
    for (int c = tid; c < 2048; c += 512) {
      int row = c >> 6;
      int off = (c & 63) << 4;
      uint4 v = *reinterpret_cast<const uint4*>(&hR[(row << 10) + (off ^ ((row & 7) << 4))]);
      *reinterpret_cast<uint4*>(dst + (row << 10) + off) = v;
    }
  }
}

__global__ __launch_bounds__(512, 4) void k_out(u16* __restrict__ hb,
                                                const float* __restrict__ inp,
                                                const u16* __restrict__ woutb,
                                                const float* __restrict__ bout) {
  __shared__ unsigned char hA[32768];
  const int tid = threadIdx.x, wid = tid >> 6, lane = tid & 63;
  const int bid = blockIdx.x;
  const int m0 = ((bid & 7) * 424 + (bid >> 3)) * 32;
  {
    const char* src = (const char*)(hb + (size_t)m0 * DD);
#pragma unroll
    for (int c = tid; c < 2048; c += 512) {
      int row = c >> 6;
      int off = (c & 63) << 4;
      uint4 v = *reinterpret_cast<const uint4*>(src + (row << 10) + off);
      *reinterpret_cast<uint4*>(&hA[(row << 10) + (off ^ ((row & 7) << 4))]) = v;
    }
  }
  __syncthreads();
  const int colbase = wid << 6;
  const int arow = lane & 15, kc = lane >> 4;
  f32x4 acc[2][4];
#pragma unroll
  for (int a = 0; a < 2; ++a)
#pragma unroll
    for (int b = 0; b < 4; ++b) acc[a][b] = (f32x4){0.f, 0.f, 0.f, 0.f};
  const u16* bp[4];
#pragma unroll
  for (int ni = 0; ni < 4; ++ni)
    bp[ni] = woutb + (size_t)(colbase + ni * 16 + arow) * 1024;
  float bov[4];
#pragma unroll
  for (int ni = 0; ni < 4; ++ni) bov[ni] = bout[colbase + ni * 16 + arow];

#pragma unroll 2
  for (int kb = 0; kb < 16; ++kb) {
    const int k = kb * 32 + kc * 8;
    s16x8 aF[2], bF[4];
#pragma unroll
    for (int mi = 0; mi < 2; ++mi) {
      int row = mi * 16 + arow;
      aF[mi] = *reinterpret_cast<const s16x8*>(&hA[(row << 10) + ((k * 2) ^ ((row & 7) << 4))]);
    }
#pragma unroll
    for (int ni = 0; ni < 4; ++ni) bF[ni] = *reinterpret_cast<const s16x8*>(bp[ni] + k);
#pragma unroll
    for (int mi = 0; mi < 2; ++mi)
#pragma unroll
      for (int ni = 0; ni < 4; ++ni)
        acc[mi][ni] = __builtin_amdgcn_mfma_f32_16x16x32_bf16(aF[mi], bF[ni], acc[mi][ni], 0, 0, 0);
  }
  __syncthreads();
  {
#pragma unroll
    for (int c = tid; c < 2048; c += 512) {
      int row = c >> 6;
      int off8 = (c & 63) * 8;
      const float* sp = inp + (size_t)(m0 + row) * DD + off8;
      float4 v0 = *reinterpret_cast<const float4*>(sp);
      float4 v1 = *reinterpret_cast<const float4*>(sp + 4);
      uint4 o;
      o.x = (u32)f2b(v0.x) | ((u32)f2b(v0.y) << 16);
      o.y = (u32)f2b(v0.z) | ((u32)f2b(v0.w) << 16);
      o.z = (u32)f2b(v1.x) | ((u32)f2b(v1.y) << 16);
      o.w = (u32)f2b(v1.z) | ((u32)f2b(v1.w) << 16);
      *reinterpret_cast<uint4*>(&hA[(row << 10) + ((off8 * 2) ^ ((row & 7) << 4))]) = o;
    }
  }
  __syncthreads();
#pragma unroll 2
  for (int kb = 0; kb < 16; ++kb) {
    const int k = kb * 32 + kc * 8;
    s16x8 aF[2], bF[4];
#pragma unroll
    for (int mi = 0; mi < 2; ++mi) {
      int row = mi * 16 + arow;
      aF[mi] = *reinterpret_cast<const s16x8*>(&hA[(row << 10) + ((k * 2) ^ ((row & 7) << 4))]);
    }
#pragma unroll
    for (int ni = 0; ni < 4; ++ni) bF[ni] = *reinterpret_cast<const s16x8*>(bp[ni] + 512 + k);
#pragma unroll
    for (int mi = 0; mi < 2; ++mi)
#pragma unroll
      for (int ni = 0; ni < 4; ++ni)
        acc[mi][ni] = __builtin_amdgcn_mfma_f32_16x16x32_bf16(aF[mi], bF[ni], acc[mi][ni], 0, 0, 0);
  }
  __syncthreads();
#pragma unroll
  for (int mi = 0; mi < 2; ++mi)
#pragma unroll
    for (int q = 0; q < 4; ++q) {
      const int row = mi * 16 + kc * 4 + q;
#pragma unroll
      for (int ni = 0; ni < 4; ++ni) {
        const int col = colbase + ni * 16 + arow;
        float v = fmaxf(acc[mi][ni][q] + bov[ni], 0.f);
        *reinterpret_cast<u16*>(&hA[(row << 10) + ((col * 2) ^ ((row & 7) << 4))]) = f2b(v);
      }
    }
  __syncthreads();
  {
    char* dst = (char*)(hb + (size_t)m0 * DD);
#pragma unroll
    for (int c = tid; c < 2048; c += 512) {
      int row = c >> 6;
      int off = (c & 63) << 4;
      uint4 v = *reinterpret_cast<const uint4*>(&hA[(row << 10) + (off ^ ((row & 7) << 4))]);
      *reinterpret_cast<uint4*>(dst + (row << 10) + off) = v;
    }
  }
}

// classifier split-K partials: 16-way K split (512 blocks -> 2/CU)
__global__ __launch_bounds__(256) void k_cls(const u16* __restrict__ outb,
                                             const u16* __restrict__ wclsb,
                                             float* __restrict__ part) {
  const int tid = threadIdx.x, wid = tid >> 6, lane = tid & 63;
  const int rbase = blockIdx.x * 64 + wid * 16;
  const int ks = blockIdx.y;
  const int arow = lane & 15, kc = lane >> 4;
  f32x4 acc[4];
#pragma unroll
  for (int ni = 0; ni < 4; ++ni) acc[ni] = (f32x4){0.f, 0.f, 0.f, 0.f};
  const u16* ap = outb + (size_t)(rbase + arow) * KCLS;
  const int kbase = ks * (KCLS / 16);
#pragma unroll 2
  for (int kb = 0; kb < (KCLS / 16) / 32; ++kb) { // 53
    const int k = kbase + kb * 32 + kc * 8;
    s16x8 aF = *reinterpret_cast<const s16x8*>(ap + k);
#pragma unroll
    for (int ni = 0; ni < 4; ++ni) {
      s16x8 bF = *reinterpret_cast<const s16x8*>(wclsb + (size_t)(ni * 16 + arow) * KCLS + k);
      acc[ni] = __builtin_amdgcn_mfma_f32_16x16x32_bf16(aF, bF, acc[ni], 0, 0, 0);
    }
  }
#pragma unroll
  for (int ni = 0; ni < 4; ++ni)
#pragma unroll
    for (int q = 0; q < 4; ++q)
      part[(size_t)(ks * 2048 + rbase + kc * 4 + q) * 64 + ni * 16 + arow] = acc[ni][q];
}

__global__ void k_clsred(const float* __restrict__ part, const float* __restrict__ bcls,
                         float* __restrict__ outp) {
  int idx = blockIdx.x * 256 + threadIdx.x;
  if (idx >= RR * CCC) return;
  int r = idx / CCC;
  int c = idx - r * CCC;
  float s = bcls[c];
#pragma unroll
  for (int ks = 0; ks < 16; ++ks) s += part[(size_t)(ks * 2048 + r) * 64 + c];
  outp[idx] = s;
}

// ---------------- launcher ----------------

extern "C" void kernel_launch(void* const* d_in, const int* in_sizes, int n_in,
                              void* d_out, int out_size, void* d_ws, size_t ws_size,
                              hipStream_t stream) {
  (void)in_sizes; (void)n_in; (void)out_size;
  const int*   so     = (const int*)d_in[1];
  const float* inp    = (const float*)d_in[2];
  const float* matrix = (const float*)d_in[3];
  const float* w3w    = (const float*)d_in[4];
  const float* b3w    = (const float*)d_in[5];
  const float* w3u    = (const float*)d_in[6];
  const float* b3u    = (const float*)d_in[7];
  const float* w4w    = (const float*)d_in[8];
  const float* b4w    = (const float*)d_in[9];
  const float* w5w    = (const float*)d_in[10];
  const float* b5w    = (const float*)d_in[11];
  const float* w5u    = (const float*)d_in[12];
  const float* b5u    = (const float*)d_in[13];
  const float* wout   = (const float*)d_in[14];
  const float* bout   = (const float*)d_in[15];
  const float* wcls   = (const float*)d_in[16];
  const float* bcls   = (const float*)d_in[17];

  char* ws = (char*)d_ws;
  u16*   hb    = (u16*)  (ws + 0);          // 111,149,056
  float* Bmat  = (float*)(ws + 111149056);  // 417,792
  u16*   ar    = (u16*)  (ws + 111566848);  // 4,194,304
  u16*   gb    = (u16*)  (ws + 115761152);  // 12,589,056 (4098 rows)
  u16*   Wcat  = (u16*)  (ws + 128350208);  // 1,572,864
  u16*   w3ub  = (u16*)  (ws + 129923072);  // 524,288
  u16*   w5ub  = (u16*)  (ws + 130447360);  // 524,288
  u16*   woutb = (u16*)  (ws + 130971648);  // 1,048,576
  u16*   wclsb = (u16*)  (ws + 132020224);  // 3,473,408
  float* bias  = (float*)(ws + 135493632);  // 6,144
  // half-slice buffers (proven path, ws >= 250.8 MB)
  u16*   rvh_s = (u16*)  (ws + 139694080);  // 55,574,528
  unsigned char* zb8_s = (unsigned char*)(ws + 195268608); // 27,787,264
  // full-M buffers (if ws >= 306.4 MB)
  u16*   rvh_f = (u16*)  (ws + 139694080);  // 111,149,056
  unsigned char* zb8_f = (unsigned char*)(ws + 250843136); // 55,574,528 -> 306,417,664
  u16*   outb  = (u16*)  (ws + 139694080);  // reuses rvh region after GRU
  float* part  = (float*)(ws + 115761152);  // reuses gb (12.6MB >= 16*2048*64*4)
  const bool fullM = ws_size >= 306417664ULL;
  const bool big   = ws_size >= 250843136ULL;

  // prep (Bmat must precede k_redcvt)
  k_gatherB<<<dim3(2048), dim3(64), 0, stream>>>(so, matrix, Bmat);
  k_cvt4<<<dim3(256),   dim3(256), 0, stream>>>(w3u, w3ub, 65536);
  k_cvt4<<<dim3(256),   dim3(256), 0, stream>>>(w5u, w5ub, 65536);
  k_cvt4<<<dim3(512),   dim3(256), 0, stream>>>(wout, woutb, 131072);
  k_wcls<<<dim3(64),    dim3(256), 0, stream>>>(wcls, wclsb);
  k_wcat<<<dim3(3072),  dim3(256), 0, stream>>>(w3w, w4w, w5w, Wcat);
  k_bias<<<dim3(2), dim3(256), 0, stream>>>(b3w, b3u, b4w, b5w, b5u, bias);

  // 3 GRU time steps
  for (int t = 0; t < 3; ++t) {
    if (t == 0)
      k_redcvt<<<dim3(2048), dim3(256), 0, stream>>>(inp, Bmat, hb, ar);
    else
      k_reduce<<<dim3(2048), dim3(256), 0, stream>>>(hb, Bmat, ar);
    k_agemm<<<dim3(64, 24), dim3(256), 0, stream>>>(ar, Wcat, gb);
    if (fullM) {
      k_g1<<<dim3(3392), dim3(512), 0, stream>>>(hb, w3ub, gb, Bmat, bias, rvh_f, zb8_f, 0);
      k_g2<<<dim3(3392), dim3(512), 0, stream>>>(hb, w5ub, gb, Bmat, bias, rvh_f, zb8_f, 0);
    } else if (big) {
      k_g1<<<dim3(1696), dim3(512), 0, stream>>>(hb, w3ub, gb, Bmat, bias, rvh_s, zb8_s, 0);
      k_g2<<<dim3(1696), dim3(512), 0, stream>>>(hb, w5ub, gb, Bmat, bias, rvh_s, zb8_s, 0);
      k_g1<<<dim3(1696), dim3(512), 0, stream>>>(hb, w3ub, gb, Bmat, bias, rvh_s, zb8_s, MHALF);
      k_g2<<<dim3(1696), dim3(512), 0, stream>>>(hb, w5ub, gb, Bmat, bias, rvh_s, zb8_s, MHALF);
    } else {
      k_gru<<<dim3(3392), dim3(512), 0, stream>>>(hb, w3ub, w5ub, gb, Bmat, bias);
    }
  }

  // output projection + classifier
  if (big) {
    k_out2<<<dim3(3392), dim3(512), 0, stream>>>(hb, inp, woutb, bout, outb);
    k_cls<<<dim3(32, 16), dim3(256), 0, stream>>>(outb, wclsb, part);
  } else {
    k_out<<<dim3(3392), dim3(512), 0, stream>>>(hb, inp, woutb, bout);
    k_cls<<<dim3(32, 16), dim3(256), 0, stream>>>(hb, wclsb, part);
  }
  k_clsred<<<dim3(408), dim3(256), 0, stream>>>(part, bcls, (float*)d_out);
}

// Round 16
// 1349.476 us; speedup vs baseline: 1.0436x; 1.0436x over previous
//
#include <hip/hip_runtime.h>
#include <stdint.h>

// Problem constants
#define RR 2048
#define NND 53
#define DD 512
#define CCC 51
#define MM (RR*NND)          // 108544
#define MHALF 54272
#define KCLS (NND*DD)        // 27136
#define MAGIC53 1296593901ULL // ceil(2^36/53); valid for m < 4e9

using u16 = unsigned short;
using u32 = unsigned int;
using f32x4 = __attribute__((ext_vector_type(4))) float;
using s16x8 = __attribute__((ext_vector_type(8))) short;

static __device__ __forceinline__ u16 f2b(float f) {
  u32 x = __float_as_uint(f);
  x += 0x7FFFu + ((x >> 16) & 1u);
  return (u16)(x >> 16);
}
static __device__ __forceinline__ float b2f(u16 u) {
  return __uint_as_float(((u32)u) << 16);
}
static __device__ __forceinline__ float fsigm(float x) {
  return __builtin_amdgcn_rcpf(1.f + __builtin_amdgcn_exp2f(-1.442695041f * x));
}
static __device__ __forceinline__ float ftanh(float x) {
  return 1.f - 2.f * __builtin_amdgcn_rcpf(1.f + __builtin_amdgcn_exp2f(2.885390082f * x));
}

// ---------------- prep kernels ----------------

__global__ void k_cvt4(const float* __restrict__ src, u16* __restrict__ dst, int n4) {
  int i = blockIdx.x * 256 + threadIdx.x;
  if (i >= n4) return;
  float4 v = *reinterpret_cast<const float4*>(src + (size_t)i * 4);
  uint2 o;
  o.x = (u32)f2b(v.x) | ((u32)f2b(v.y) << 16);
  o.y = (u32)f2b(v.z) | ((u32)f2b(v.w) << 16);
  *reinterpret_cast<uint2*>(dst + (size_t)i * 4) = o;
}

__global__ void k_wcat(const float* __restrict__ w3w, const float* __restrict__ w4w,
                       const float* __restrict__ w5w, u16* __restrict__ Wcat) {
  int idx = blockIdx.x * 256 + threadIdx.x;
  if (idx >= 1536 * 512) return;
  int j = idx >> 9, k = idx & 511;
  const float* w = (j < 512) ? w3w : (j < 1024) ? w4w : w5w;
  int jj = j & 511;
  float v = w[(size_t)jj * 1024 + k] + w[(size_t)jj * 1024 + 512 + k];
  Wcat[idx] = f2b(v);
}

__global__ void k_wcls(const float* __restrict__ wcls, u16* __restrict__ dst) {
  int cc = blockIdx.x; // 0..63
  for (int t = threadIdx.x; t < KCLS; t += 256)
    dst[(size_t)cc * KCLS + t] = (cc < CCC) ? f2b(wcls[(size_t)cc * KCLS + t]) : (u16)0;
}

__global__ void k_gatherB(const int* __restrict__ so, const float* __restrict__ matrix,
                          float* __restrict__ Bmat) {
  int r = blockIdx.x;
  int c = threadIdx.x;
  if (c < CCC) {
    int s = so[2 * r], o = so[2 * r + 1];
    Bmat[r * CCC + c] = matrix[((size_t)s * 151 + o) * CCC + c];
  }
}

__global__ void k_bias(const float* __restrict__ b3w, const float* __restrict__ b3u,
                       const float* __restrict__ b4w, const float* __restrict__ b5w,
                       const float* __restrict__ b5u, float* __restrict__ bias) {
  int j = blockIdx.x * 256 + threadIdx.x;
  if (j >= 512) return;
  bias[j]        = b3w[j] + b3u[j];
  bias[512 + j]  = b4w[j] + b3u[j];
  bias[1024 + j] = b5w[j] + b5u[j];
}

// ---------------- per-step kernels ----------------

// t=0 fused: inp f32 -> hb bf16 (full copy) + ar reduction in the same pass
__global__ __launch_bounds__(256) void k_redcvt(const float* __restrict__ inp,
                                                const float* __restrict__ Bmat,
                                                u16* __restrict__ hb,
                                                u16* __restrict__ ar) {
  __shared__ float Bs[CCC];
  int r = blockIdx.x, tid = threadIdx.x;
  if (tid < CCC) Bs[tid] = Bmat[r * CCC + tid];
  __syncthreads();
  int d0 = tid * 2;
  const float* irow = inp + (size_t)r * NND * DD;
  u16* hrow = hb + (size_t)r * NND * DD;
  float a0 = 0.f, a1 = 0.f, h0 = 0.f, h1 = 0.f;
  for (int i = 0; i < NND; ++i) {
    float2 v = *reinterpret_cast<const float2*>(irow + (size_t)i * DD + d0);
    *reinterpret_cast<u32*>(hrow + (size_t)i * DD + d0) =
        (u32)f2b(v.x) | ((u32)f2b(v.y) << 16);
    if (i < 2) { h0 += v.x; h1 += v.y; }
    else       { float s = Bs[i - 2]; a0 += s * v.x; a1 += s * v.y; }
  }
  *reinterpret_cast<u32*>(ar + (size_t)(2 * r) * DD + d0) =
      (u32)f2b(a0) | ((u32)f2b(a1) << 16);
  *reinterpret_cast<u32*>(ar + (size_t)(2 * r + 1) * DD + d0) =
      (u32)f2b(h0) | ((u32)f2b(h1) << 16);
}

__global__ __launch_bounds__(256) void k_reduce(const u16* __restrict__ hb,
                                                const float* __restrict__ Bmat,
                                                u16* __restrict__ ar) {
  __shared__ float Bs[CCC];
  int r = blockIdx.x, tid = threadIdx.x;
  if (tid < CCC) Bs[tid] = Bmat[r * CCC + tid];
  __syncthreads();
  int d0 = tid * 2;
  const u16* hrow = hb + (size_t)r * NND * DD;
  float a0 = 0.f, a1 = 0.f;
  for (int c = 0; c < CCC; ++c) {
    u32 v = *reinterpret_cast<const u32*>(hrow + (size_t)(2 + c) * DD + d0);
    float s = Bs[c];
    a0 += s * b2f((u16)v);
    a1 += s * b2f((u16)(v >> 16));
  }
  u32 v0 = *reinterpret_cast<const u32*>(hrow + 0 * DD + d0);
  u32 v1 = *reinterpret_cast<const u32*>(hrow + 1 * DD + d0);
  float h0 = b2f((u16)v0) + b2f((u16)v1);
  float h1 = b2f((u16)(v0 >> 16)) + b2f((u16)(v1 >> 16));
  *reinterpret_cast<u32*>(ar + (size_t)(2 * r) * DD + d0) =
      (u32)f2b(a0) | ((u32)f2b(a1) << 16);
  *reinterpret_cast<u32*>(ar + (size_t)(2 * r + 1) * DD + d0) =
      (u32)f2b(h0) | ((u32)f2b(h1) << 16);
}

__global__ __launch_bounds__(256) void k_agemm(const u16* __restrict__ ar,
                                               const u16* __restrict__ Wcat,
                                               u16* __restrict__ gb) {
  const int tid = threadIdx.x, wid = tid >> 6, lane = tid & 63;
  const int m0 = blockIdx.x * 64 + wid * 16;
  const int n0 = blockIdx.y * 64;
  const int arow = lane & 15, kc = lane >> 4;
  f32x4 acc[4];
#pragma unroll
  for (int ni = 0; ni < 4; ++ni) acc[ni] = (f32x4){0.f, 0.f, 0.f, 0.f};
  const u16* ap = ar + (size_t)(m0 + arow) * DD;
#pragma unroll 2
  for (int kb = 0; kb < 16; ++kb) {
    const int k = kb * 32 + kc * 8;
    s16x8 aF = *reinterpret_cast<const s16x8*>(ap + k);
#pragma unroll
    for (int ni = 0; ni < 4; ++ni) {
      s16x8 bF = *reinterpret_cast<const s16x8*>(Wcat + (size_t)(n0 + ni * 16 + arow) * DD + k);
      acc[ni] = __builtin_amdgcn_mfma_f32_16x16x32_bf16(aF, bF, acc[ni], 0, 0, 0);
    }
  }
#pragma unroll
  for (int ni = 0; ni < 4; ++ni)
#pragma unroll
    for (int q = 0; q < 4; ++q)
      gb[(size_t)(m0 + kc * 4 + q) * 1536 + n0 + ni * 16 + arow] = f2b(acc[ni][q]);
}

// ===== split-GEMM GRU: G1 = h@w3u^T + gate epilogue (z->u8 direct scatter) =====
// Half-M slices keep the g1->g2 working set (~139MB) L3-resident — full-M
// (r15) spilled L3 (278MB > 256MB) and regressed +58us. Keep half-slice.
__global__ __launch_bounds__(512, 2) void k_g1(const u16* __restrict__ hb,
                                               const u16* __restrict__ w3ub,
                                               const u16* __restrict__ gb,
                                               const float* __restrict__ Bmat,
                                               const float* __restrict__ bias,
                                               u16* __restrict__ rvh,
                                               unsigned char* __restrict__ zb8,
                                               int mbase) {
  __shared__ unsigned char lds[49152]; // A[0,16K) | B[16K,32K) | gS[32K,48K)
  __shared__ float sRowS[128];
  __shared__ int   fRowS[128];
  const int tid = threadIdx.x, wid = tid >> 6, lane = tid & 63;
  const int wg = ((blockIdx.x & 7) * 212 + (blockIdx.x >> 3)); // XCD swizzle (1696=8*212)
  const int m0 = mbase + (wg >> 2) * 128;
  const int n0 = (wg & 3) * 128;
  const int r0 = (int)(((unsigned long long)m0 * MAGIC53) >> 36);

  {
    const uint4* gsrc = reinterpret_cast<const uint4*>(gb);
    uint4* gdst = reinterpret_cast<uint4*>(lds + 32768);
#pragma unroll
    for (int c = tid; c < 1024; c += 512) {
      int slot = c >> 7, within = c & 127;
      gdst[c] = gsrc[(size_t)(2 * r0 + slot) * 192 + within];
    }
  }
  if (tid < 128) {
    int mg = m0 + tid;
    int rr = (int)(((unsigned long long)mg * MAGIC53) >> 36);
    int ii = mg - rr * 53;
    bool useA = (ii < 2);
    sRowS[tid] = useA ? 1.0f : Bmat[rr * CCC + (ii - 2)];
    fRowS[tid] = ((rr - r0) << 1) | (useA ? 0 : 1);
  }

  const int arow = lane & 15, kc = lane >> 4;
  const int R = (wid >> 1) * 32, C = (wid & 1) * 64;
  const int lrow = lane >> 3, linrow = (lane & 7) * 16;
  const unsigned char* ab = (const unsigned char*)hb;
  const unsigned char* bb = (const unsigned char*)w3ub;

  f32x4 acc[2][4];
#pragma unroll
  for (int a = 0; a < 2; ++a)
#pragma unroll
    for (int b = 0; b < 4; ++b) acc[a][b] = (f32x4){0.f, 0.f, 0.f, 0.f};

  for (int ks = 0; ks < 8; ++ks) {
    __syncthreads();
#pragma unroll
    for (int r = 0; r < 2; ++r) {
      int rowA = (r * 8 + wid) * 8 + lrow;
      int inr0 = linrow ^ ((rowA & 7) << 4);
      __builtin_amdgcn_global_load_lds(
          (const unsigned int*)(ab + (size_t)(m0 + rowA) * 1024 + ks * 128 + inr0),
          (unsigned int*)(lds + (r * 8 + wid) * 1024 + lane * 16), 16, 0, 0);
      __builtin_amdgcn_global_load_lds(
          (const unsigned int*)(bb + (size_t)(n0 + rowA) * 1024 + ks * 128 + inr0),
          (unsigned int*)(lds + 16384 + (r * 8 + wid) * 1024 + lane * 16), 16, 0, 0);
    }
    __syncthreads();
#pragma unroll
    for (int ks2 = 0; ks2 < 2; ++ks2) {
      const int kb = kc * 16 + ks2 * 64;
      s16x8 aF[2], bF[4];
#pragma unroll
      for (int mi = 0; mi < 2; ++mi) {
        int row = R + mi * 16 + arow;
        aF[mi] = *reinterpret_cast<const s16x8*>(lds + row * 128 + (kb ^ ((row & 7) << 4)));
      }
#pragma unroll
      for (int ni = 0; ni < 4; ++ni) {
        int col = C + ni * 16 + arow;
        bF[ni] = *reinterpret_cast<const s16x8*>(lds + 16384 + col * 128 + (kb ^ ((col & 7) << 4)));
      }
#pragma unroll
      for (int mi = 0; mi < 2; ++mi)
#pragma unroll
        for (int ni = 0; ni < 4; ++ni)
          acc[mi][ni] = __builtin_amdgcn_mfma_f32_16x16x32_bf16(aF[mi], bF[ni], acc[mi][ni], 0, 0, 0);
    }
  }
  __syncthreads(); // K-loop done; A/B LDS reusable as output tile

  // stage h tile (coalesced, L2-hot) into output LDS region
  {
    const unsigned char* srcb = (const unsigned char*)(hb + (size_t)m0 * 512 + n0);
#pragma unroll
    for (int j = 0; j < 4; ++j) {
      int idx = tid + j * 512;
      int row = idx >> 4, incol = (idx & 15) * 16;
      uint4 v = *reinterpret_cast<const uint4*>(srcb + (size_t)row * 1024 + incol);
      *reinterpret_cast<uint4*>(lds + row * 256 + (incol ^ ((row & 7) << 4))) = v;
    }
  }
  __syncthreads();

  const u16* gS = (const u16*)(lds + 32768);
  float bz[4], br[4];
#pragma unroll
  for (int ni = 0; ni < 4; ++ni) {
    int colg = n0 + C + ni * 16 + arow;
    bz[ni] = bias[colg];
    br[ni] = bias[512 + colg];
  }

#pragma unroll
  for (int mi = 0; mi < 2; ++mi) {
#pragma unroll
    for (int q = 0; q < 4; ++q) {
      const int row = R + mi * 16 + kc * 4 + q;
      const float s = sRowS[row];
      const u16* gp = gS + fRowS[row] * 1024;
      unsigned char* zrow = zb8 + (size_t)(m0 - mbase + row) * 512 + n0;
#pragma unroll
      for (int ni = 0; ni < 4; ++ni) {
        const int cl = C + ni * 16 + arow;
        const int colg = n0 + cl;
        const float u3 = acc[mi][ni][q];
        const float zv = fsigm(s * b2f(gp[colg]) + u3 + bz[ni]);
        const float rv = fsigm(s * b2f(gp[512 + colg]) + u3 + br[ni]);
        u16* hp = reinterpret_cast<u16*>(lds + row * 256 + ((cl * 2) ^ ((row & 7) << 4)));
        const float hval = b2f(*hp);
        *hp = f2b(rv * hval); // owner RMW: read h, write rvh
        zrow[cl] = (unsigned char)fmaf(zv, 255.f, 0.5f); // direct scatter store
      }
    }
  }
  __syncthreads();
  {
    unsigned char* dstb = (unsigned char*)(rvh + (size_t)(m0 - mbase) * 512 + n0);
#pragma unroll
    for (int j = 0; j < 4; ++j) {
      int idx = tid + j * 512;
      int row = idx >> 4, incol = (idx & 15) * 16;
      uint4 v = *reinterpret_cast<const uint4*>(lds + row * 256 + (incol ^ ((row & 7) << 4)));
      *reinterpret_cast<uint4*>(dstb + (size_t)row * 1024 + incol) = v;
    }
  }
}

// ===== G2 = rvh@w5u^T + h_new epilogue (zT LDS-staged, 57KB) =====
__global__ __launch_bounds__(512, 2) void k_g2(u16* __restrict__ hb,
                                               const u16* __restrict__ w5ub,
                                               const u16* __restrict__ gb,
                                               const float* __restrict__ Bmat,
                                               const float* __restrict__ bias,
                                               const u16* __restrict__ rvh,
                                               const unsigned char* __restrict__ zb8,
                                               int mbase) {
  __shared__ unsigned char lds[57344]; // A[0,16K)|B[16K,32K)|gS[32K,40K)|zT[40K,56K)
  __shared__ float sRowS[128];
  __shared__ int   fRowS[128];
  const int tid = threadIdx.x, wid = tid >> 6, lane = tid & 63;
  const int wg = ((blockIdx.x & 7) * 212 + (blockIdx.x >> 3));
  const int m0 = mbase + (wg >> 2) * 128;
  const int n0 = (wg & 3) * 128;
  const int r0 = (int)(((unsigned long long)m0 * MAGIC53) >> 36);

  {
    const uint4* gsrc = reinterpret_cast<const uint4*>(gb);
    uint4* gdst = reinterpret_cast<uint4*>(lds + 32768);
    if (tid < 512) {
      int slot = tid >> 6, within = tid & 63;
      gdst[tid] = gsrc[(size_t)(2 * r0 + slot) * 192 + 128 + within];
    }
  }
  // stage z-u8 tile (coalesced)
  {
    const unsigned char* zsrc = zb8 + (size_t)(m0 - mbase) * 512 + n0;
#pragma unroll
    for (int j = 0; j < 2; ++j) {
      int idx = tid + j * 512;
      int row = idx >> 3, incol = (idx & 7) * 16;
      uint4 v = *reinterpret_cast<const uint4*>(zsrc + (size_t)row * 512 + incol);
      *reinterpret_cast<uint4*>(lds + 40960 + row * 128 + incol) = v;
    }
  }
  if (tid < 128) {
    int mg = m0 + tid;
    int rr = (int)(((unsigned long long)mg * MAGIC53) >> 36);
    int ii = mg - rr * 53;
    bool useA = (ii < 2);
    sRowS[tid] = useA ? 1.0f : Bmat[rr * CCC + (ii - 2)];
    fRowS[tid] = ((rr - r0) << 1) | (useA ? 0 : 1);
  }

  const int arow = lane & 15, kc = lane >> 4;
  const int R = (wid >> 1) * 32, C = (wid & 1) * 64;
  const int lrow = lane >> 3, linrow = (lane & 7) * 16;
  const unsigned char* ab = (const unsigned char*)rvh;
  const unsigned char* bb = (const unsigned char*)w5ub;

  f32x4 acc[2][4];
#pragma unroll
  for (int a = 0; a < 2; ++a)
#pragma unroll
    for (int b = 0; b < 4; ++b) acc[a][b] = (f32x4){0.f, 0.f, 0.f, 0.f};

  for (int ks = 0; ks < 8; ++ks) {
    __syncthreads();
#pragma unroll
    for (int r = 0; r < 2; ++r) {
      int rowA = (r * 8 + wid) * 8 + lrow;
      int inr0 = linrow ^ ((rowA & 7) << 4);
      __builtin_amdgcn_global_load_lds(
          (const unsigned int*)(ab + (size_t)(m0 - mbase + rowA) * 1024 + ks * 128 + inr0),
          (unsigned int*)(lds + (r * 8 + wid) * 1024 + lane * 16), 16, 0, 0);
      __builtin_amdgcn_global_load_lds(
          (const unsigned int*)(bb + (size_t)(n0 + rowA) * 1024 + ks * 128 + inr0),
          (unsigned int*)(lds + 16384 + (r * 8 + wid) * 1024 + lane * 16), 16, 0, 0);
    }
    __syncthreads();
#pragma unroll
    for (int ks2 = 0; ks2 < 2; ++ks2) {
      const int kb = kc * 16 + ks2 * 64;
      s16x8 aF[2], bF[4];
#pragma unroll
      for (int mi = 0; mi < 2; ++mi) {
        int row = R + mi * 16 + arow;
        aF[mi] = *reinterpret_cast<const s16x8*>(lds + row * 128 + (kb ^ ((row & 7) << 4)));
      }
#pragma unroll
      for (int ni = 0; ni < 4; ++ni) {
        int col = C + ni * 16 + arow;
        bF[ni] = *reinterpret_cast<const s16x8*>(lds + 16384 + col * 128 + (kb ^ ((col & 7) << 4)));
      }
#pragma unroll
      for (int mi = 0; mi < 2; ++mi)
#pragma unroll
        for (int ni = 0; ni < 4; ++ni)
          acc[mi][ni] = __builtin_amdgcn_mfma_f32_16x16x32_bf16(aF[mi], bF[ni], acc[mi][ni], 0, 0, 0);
    }
  }
  __syncthreads();

  // stage h_old tile (coalesced) into output LDS region
  {
    const unsigned char* srcb = (const unsigned char*)(hb + (size_t)m0 * 512 + n0);
#pragma unroll
    for (int j = 0; j < 4; ++j) {
      int idx = tid + j * 512;
      int row = idx >> 4, incol = (idx & 15) * 16;
      uint4 v = *reinterpret_cast<const uint4*>(srcb + (size_t)row * 1024 + incol);
      *reinterpret_cast<uint4*>(lds + row * 256 + (incol ^ ((row & 7) << 4))) = v;
    }
  }
  __syncthreads();

  const u16* gS = (const u16*)(lds + 32768);
  const unsigned char* zT = lds + 40960;
  float bh[4];
#pragma unroll
  for (int ni = 0; ni < 4; ++ni) bh[ni] = bias[1024 + n0 + C + ni * 16 + arow];

#pragma unroll
  for (int mi = 0; mi < 2; ++mi) {
#pragma unroll
    for (int q = 0; q < 4; ++q) {
      const int row = R + mi * 16 + kc * 4 + q;
      const float s = sRowS[row];
      const u16* gp = gS + fRowS[row] * 512;
#pragma unroll
      for (int ni = 0; ni < 4; ++ni) {
        const int cl = C + ni * 16 + arow;
        const int colg = n0 + cl;
        const float hv = ftanh(acc[mi][ni][q] + s * b2f(gp[colg]) + bh[ni]);
        const float zv = (float)zT[row * 128 + cl] * (1.f / 255.f);
        u16* hp = reinterpret_cast<u16*>(lds + row * 256 + ((cl * 2) ^ ((row & 7) << 4)));
        const float ho = b2f(*hp);
        *hp = f2b(fmaf(zv, hv - ho, ho)); // owner RMW
      }
    }
  }
  __syncthreads();
  {
    unsigned char* dstb = (unsigned char*)(hb + (size_t)m0 * 512 + n0);
#pragma unroll
    for (int j = 0; j < 4; ++j) {
      int idx = tid + j * 512;
      int row = idx >> 4, incol = (idx & 15) * 16;
      uint4 v = *reinterpret_cast<const uint4*>(lds + row * 256 + (incol ^ ((row & 7) << 4)));
      *reinterpret_cast<uint4*>(dstb + (size_t)row * 1024 + incol) = v;
    }
  }
}

// ===== k_out2: out = relu([hf | inp] @ wout^T + bout) -> outb =====
__global__ __launch_bounds__(512, 2) void k_out2(const u16* __restrict__ hb,
                                                 const float* __restrict__ inp,
                                                 const u16* __restrict__ woutb,
                                                 const float* __restrict__ bout,
                                                 u16* __restrict__ outb) {
  __shared__ unsigned char lds[32768]; // A[0,16K) | B[16K,32K); reused as out tile
  const int tid = threadIdx.x, wid = tid >> 6, lane = tid & 63;
  const int wg = ((blockIdx.x & 7) * 424 + (blockIdx.x >> 3)); // 3392 = 8*424
  const int m0 = (wg >> 2) * 128;
  const int n0 = (wg & 3) * 128;

  const int arow = lane & 15, kc = lane >> 4;
  const int R = (wid >> 1) * 32, C = (wid & 1) * 64;
  const int lrow = lane >> 3, linrow = (lane & 7) * 16;
  const unsigned char* ab = (const unsigned char*)hb;
  const unsigned char* bb = (const unsigned char*)woutb; // row stride 2048 B (K=1024)

  f32x4 acc[2][4];
#pragma unroll
  for (int a = 0; a < 2; ++a)
#pragma unroll
    for (int b = 0; b < 4; ++b) acc[a][b] = (f32x4){0.f, 0.f, 0.f, 0.f};

  for (int ks = 0; ks < 16; ++ks) {
    __syncthreads();
#pragma unroll
    for (int r = 0; r < 2; ++r) {
      int rowA = (r * 8 + wid) * 8 + lrow;
      int inr0 = linrow ^ ((rowA & 7) << 4);
      if (ks < 8) {
        __builtin_amdgcn_global_load_lds(
            (const unsigned int*)(ab + (size_t)(m0 + rowA) * 1024 + ks * 128 + inr0),
            (unsigned int*)(lds + (r * 8 + wid) * 1024 + lane * 16), 16, 0, 0);
      } else {
        const float* sp = inp + (size_t)(m0 + rowA) * 512 + (((ks - 8) * 128 + inr0) >> 1);
        float4 v0 = *reinterpret_cast<const float4*>(sp);
        float4 v1 = *reinterpret_cast<const float4*>(sp + 4);
        uint4 o;
        o.x = (u32)f2b(v0.x) | ((u32)f2b(v0.y) << 16);
        o.y = (u32)f2b(v0.z) | ((u32)f2b(v0.w) << 16);
        o.z = (u32)f2b(v1.x) | ((u32)f2b(v1.y) << 16);
        o.w = (u32)f2b(v1.z) | ((u32)f2b(v1.w) << 16);
        *reinterpret_cast<uint4*>(lds + (r * 8 + wid) * 1024 + lane * 16) = o;
      }
      __builtin_amdgcn_global_load_lds(
          (const unsigned int*)(bb + (size_t)(n0 + rowA) * 2048 + ks * 128 + inr0),
          (unsigned int*)(lds + 16384 + (r * 8 + wid) * 1024 + lane * 16), 16, 0, 0);
    }
    __syncthreads();
#pragma unroll
    for (int ks2 = 0; ks2 < 2; ++ks2) {
      const int kb = kc * 16 + ks2 * 64;
      s16x8 aF[2], bF[4];
#pragma unroll
      for (int mi = 0; mi < 2; ++mi) {
        int row = R + mi * 16 + arow;
        aF[mi] = *reinterpret_cast<const s16x8*>(lds + row * 128 + (kb ^ ((row & 7) << 4)));
      }
#pragma unroll
      for (int ni = 0; ni < 4; ++ni) {
        int col = C + ni * 16 + arow;
        bF[ni] = *reinterpret_cast<const s16x8*>(lds + 16384 + col * 128 + (kb ^ ((col & 7) << 4)));
      }
#pragma unroll
      for (int mi = 0; mi < 2; ++mi)
#pragma unroll
        for (int ni = 0; ni < 4; ++ni)
          acc[mi][ni] = __builtin_amdgcn_mfma_f32_16x16x32_bf16(aF[mi], bF[ni], acc[mi][ni], 0, 0, 0);
    }
  }
  __syncthreads();

  float bov[4];
#pragma unroll
  for (int ni = 0; ni < 4; ++ni) bov[ni] = bout[n0 + C + ni * 16 + arow];

#pragma unroll
  for (int mi = 0; mi < 2; ++mi)
#pragma unroll
    for (int q = 0; q < 4; ++q) {
      const int row = R + mi * 16 + kc * 4 + q;
#pragma unroll
      for (int ni = 0; ni < 4; ++ni) {
        const int cl = C + ni * 16 + arow;
        float v = fmaxf(acc[mi][ni][q] + bov[ni], 0.f);
        *reinterpret_cast<u16*>(lds + row * 256 + ((cl * 2) ^ ((row & 7) << 4))) = f2b(v);
      }
    }
  __syncthreads();
  {
    unsigned char* dstb = (unsigned char*)(outb + (size_t)m0 * 512 + n0);
#pragma unroll
    for (int j = 0; j < 4; ++j) {
      int idx = tid + j * 512;
      int row = idx >> 4, incol = (idx & 15) * 16;
      uint4 v = *reinterpret_cast<const uint4*>(lds + row * 256 + (incol ^ ((row & 7) << 4)));
      *reinterpret_cast<uint4*>(dstb + (size_t)row * 1024 + incol) = v;
    }
  }
}

// ===== fallback kernels (only used if ws too small; proven r5 path) =====
__global__ __launch_bounds__(512, 4) void k_gru(u16* __restrict__ hb,
                                                const u16* __restrict__ w3ub,
                                                const u16* __restrict__ w5ub,
                                                const u16* __restrict__ gb,
                                                const float* __restrict__ Bmat,
                                                const float* __restrict__ bias) {
  __shared__ unsigned char hA[32768];
  __shared__ unsigned char hR[32768];
  __shared__ u16 gS[4][1536];
  __shared__ float sRow[32];
  __shared__ int   fRow[32];

  const int tid = threadIdx.x;
  const int wid = tid >> 6;
  const int lane = tid & 63;
  const int bid = blockIdx.x;
  const int m0 = ((bid & 7) * 424 + (bid >> 3)) * 32;
  const int r0 = (int)(((unsigned long long)m0 * MAGIC53) >> 36);

  {
    const char* src = (const char*)(hb + (size_t)m0 * DD);
#pragma unroll
    for (int c = tid; c < 2048; c += 512) {
      int row = c >> 6;
      int off = (c & 63) << 4;
      uint4 v = *reinterpret_cast<const uint4*>(src + (row << 10) + off);
      *reinterpret_cast<uint4*>(&hA[(row << 10) + (off ^ ((row & 7) << 4))]) = v;
    }
  }
  {
    const uint4* gsrc = reinterpret_cast<const uint4*>(gb + (size_t)(2 * r0) * 1536);
    uint4* gdst = reinterpret_cast<uint4*>(&gS[0][0]);
#pragma unroll
    for (int c = tid; c < 768; c += 512) gdst[c] = gsrc[c];
  }
  if (tid < 32) {
    int mg = m0 + tid;
    int rr = (int)(((unsigned long long)mg * MAGIC53) >> 36);
    int ii = mg - rr * 53;
    bool useA = (ii < 2);
    sRow[tid] = useA ? 1.0f : Bmat[rr * CCC + (ii - 2)];
    fRow[tid] = ((rr - r0) << 1) | (useA ? 0 : 1);
  }
  __syncthreads();

  const int colbase = wid << 6;
  const int arow = lane & 15;
  const int kc = lane >> 4;

  float bzv[4], brv[4], bhv[4];
#pragma unroll
  for (int ni = 0; ni < 4; ++ni) {
    int col = colbase + ni * 16 + arow;
    bzv[ni] = bias[col];
    brv[ni] = bias[512 + col];
    bhv[ni] = bias[1024 + col];
  }

  f32x4 acc[2][4];
#pragma unroll
  for (int a = 0; a < 2; ++a)
#pragma unroll
    for (int b = 0; b < 4; ++b) acc[a][b] = (f32x4){0.f, 0.f, 0.f, 0.f};

  const u16* b1p[4];
#pragma unroll
  for (int ni = 0; ni < 4; ++ni)
    b1p[ni] = w3ub + (size_t)(colbase + ni * 16 + arow) * DD;

#pragma unroll 2
  for (int kb = 0; kb < 16; ++kb) {
    const int k = kb * 32 + kc * 8;
    s16x8 aF[2], bF[4];
#pragma unroll
    for (int mi = 0; mi < 2; ++mi) {
      int row = mi * 16 + arow;
      aF[mi] = *reinterpret_cast<const s16x8*>(&hA[(row << 10) + ((k * 2) ^ ((row & 7) << 4))]);
    }
#pragma unroll
    for (int ni = 0; ni < 4; ++ni)
      bF[ni] = *reinterpret_cast<const s16x8*>(b1p[ni] + k);
#pragma unroll
    for (int mi = 0; mi < 2; ++mi)
#pragma unroll
      for (int ni = 0; ni < 4; ++ni)
        acc[mi][ni] = __builtin_amdgcn_mfma_f32_16x16x32_bf16(aF[mi], bF[ni], acc[mi][ni], 0, 0, 0);
  }

  u32 zpk[2][4][2];
#pragma unroll
  for (int mi = 0; mi < 2; ++mi) {
#pragma unroll
    for (int q = 0; q < 4; ++q) {
      const int row = mi * 16 + kc * 4 + q;
      const float s = sRow[row];
      const u16* gp = &gS[0][0] + fRow[row] * 1536;
#pragma unroll
      for (int ni = 0; ni < 4; ++ni) {
        const int col = colbase + ni * 16 + arow;
        const float u3 = acc[mi][ni][q];
        const float t3 = s * b2f(gp[col]);
        const float t4 = s * b2f(gp[512 + col]);
        const float zv = fsigm(t3 + u3 + bzv[ni]);
        const float rv = fsigm(t4 + u3 + brv[ni]);
        const float hval = b2f(*reinterpret_cast<const u16*>(
            &hA[(row << 10) + ((col * 2) ^ ((row & 7) << 4))]));
        *reinterpret_cast<u16*>(&hR[(row << 10) + ((col * 2) ^ ((row & 7) << 4))]) =
            f2b(rv * hval);
        const u32 zb2 = f2b(zv);
        if (q == 0)      zpk[mi][ni][0] = zb2;
        else if (q == 1) zpk[mi][ni][0] |= zb2 << 16;
        else if (q == 2) zpk[mi][ni][1] = zb2;
        else             zpk[mi][ni][1] |= zb2 << 16;
      }
    }
  }
  __syncthreads();

#pragma unroll
  for (int a = 0; a < 2; ++a)
#pragma unroll
    for (int b = 0; b < 4; ++b) acc[a][b] = (f32x4){0.f, 0.f, 0.f, 0.f};
  const u16* b2p[4];
#pragma unroll
  for (int ni = 0; ni < 4; ++ni)
    b2p[ni] = w5ub + (size_t)(colbase + ni * 16 + arow) * DD;
#pragma unroll 2
  for (int kb = 0; kb < 16; ++kb) {
    const int k = kb * 32 + kc * 8;
    s16x8 aF[2], bF[4];
#pragma unroll
    for (int mi = 0; mi < 2; ++mi) {
      int row = mi * 16 + arow;
      aF[mi] = *reinterpret_cast<const s16x8*>(&hR[(row << 10) + ((k * 2) ^ ((row & 7) << 4))]);
    }
#pragma unroll
    for (int ni = 0; ni < 4; ++ni)
      bF[ni] = *reinterpret_cast<const s16x8*>(b2p[ni] + k);
#pragma unroll
    for (int mi = 0; mi < 2; ++mi)
#pragma unroll
      for (int ni = 0; ni < 4; ++ni)
        acc[mi][ni] = __builtin_amdgcn_mfma_f32_16x16x32_bf16(aF[mi], bF[ni], acc[mi][ni], 0, 0, 0);
  }
  __syncthreads();

#pragma unroll
  for (int mi = 0; mi < 2; ++mi) {
#pragma unroll
    for (int q = 0; q < 4; ++q) {
      const int row = mi * 16 + kc * 4 + q;
      const float s = sRow[row];
      const u16* gp = &gS[0][0] + fRow[row] * 1536;
#pragma unroll
      for (int ni = 0; ni < 4; ++ni) {
        const int col = colbase + ni * 16 + arow;
        const float g5 = s * b2f(gp[1024 + col]);
        const float hv = ftanh(acc[mi][ni][q] + g5 + bhv[ni]);
        const float zv = b2f((u16)(zpk[mi][ni][q >> 1] >> ((q & 1) * 16)));
        const float ho = b2f(*reinterpret_cast<const u16*>(
            &hA[(row << 10) + ((col * 2) ^ ((row & 7) << 4))]));
        const float hnew = fmaf(zv, hv - ho, ho);
        *reinterpret_cast<u16*>(&hR[(row << 10) + ((col * 2) ^ ((row & 7) << 4))]) = f2b(hnew);
      }
    }
  }
  __syncthreads();
  {
    char* dst = (char*)(hb + (size_t)m0 * DD);
#pragma unroll
    for (int c = tid; c < 2048; c += 512) {
      int row = c >> 6;
      int off = (c & 63) << 4;
      uint4 v = *reinterpret_cast<const uint4*>(&hR[(row << 10) + (off ^ ((row & 7) << 4))]);
      *reinterpret_cast<uint4*>(dst + (row << 10) + off) = v;
    }
  }
}

__global__ __launch_bounds__(512, 4) void k_out(u16* __restrict__ hb,
                                                const float* __restrict__ inp,
                                                const u16* __restrict__ woutb,
                                                const float* __restrict__ bout) {
  __shared__ unsigned char hA[32768];
  const int tid = threadIdx.x, wid = tid >> 6, lane = tid & 63;
  const int bid = blockIdx.x;
  const int m0 = ((bid & 7) * 424 + (bid >> 3)) * 32;
  {
    const char* src = (const char*)(hb + (size_t)m0 * DD);
#pragma unroll
    for (int c = tid; c < 2048; c += 512) {
      int row = c >> 6;
      int off = (c & 63) << 4;
      uint4 v = *reinterpret_cast<const uint4*>(src + (row << 10) + off);
      *reinterpret_cast<uint4*>(&hA[(row << 10) + (off ^ ((row & 7) << 4))]) = v;
    }
  }
  __syncthreads();
  const int colbase = wid << 6;
  const int arow = lane & 15, kc = lane >> 4;
  f32x4 acc[2][4];
#pragma unroll
  for (int a = 0; a < 2; ++a)
#pragma unroll
    for (int b = 0; b < 4; ++b) acc[a][b] = (f32x4){0.f, 0.f, 0.f, 0.f};
  const u16* bp[4];
#pragma unroll
  for (int ni = 0; ni < 4; ++ni)
    bp[ni] = woutb + (size_t)(colbase + ni * 16 + arow) * 1024;
  float bov[4];
#pragma unroll
  for (int ni = 0; ni < 4; ++ni) bov[ni] = bout[colbase + ni * 16 + arow];

#pragma unroll 2
  for (int kb = 0; kb < 16; ++kb) {
    const int k = kb * 32 + kc * 8;
    s16x8 aF[2], bF[4];
#pragma unroll
    for (int mi = 0; mi < 2; ++mi) {
      int row = mi * 16 + arow;
      aF[mi] = *reinterpret_cast<const s16x8*>(&hA[(row << 10) + ((k * 2) ^ ((row & 7) << 4))]);
    }
#pragma unroll
    for (int ni = 0; ni < 4; ++ni) bF[ni] = *reinterpret_cast<const s16x8*>(bp[ni] + k);
#pragma unroll
    for (int mi = 0; mi < 2; ++mi)
#pragma unroll
      for (int ni = 0; ni < 4; ++ni)
        acc[mi][ni] = __builtin_amdgcn_mfma_f32_16x16x32_bf16(aF[mi], bF[ni], acc[mi][ni], 0, 0, 0);
  }
  __syncthreads();
  {
#pragma unroll
    for (int c = tid; c < 2048; c += 512) {
      int row = c >> 6;
      int off8 = (c & 63) * 8;
      const float* sp = inp + (size_t)(m0 + row) * DD + off8;
      float4 v0 = *reinterpret_cast<const float4*>(sp);
      float4 v1 = *reinterpret_cast<const float4*>(sp + 4);
      uint4 o;
      o.x = (u32)f2b(v0.x) | ((u32)f2b(v0.y) << 16);
      o.y = (u32)f2b(v0.z) | ((u32)f2b(v0.w) << 16);
      o.z = (u32)f2b(v1.x) | ((u32)f2b(v1.y) << 16);
      o.w = (u32)f2b(v1.z) | ((u32)f2b(v1.w) << 16);
      *reinterpret_cast<uint4*>(&hA[(row << 10) + ((off8 * 2) ^ ((row & 7) << 4))]) = o;
    }
  }
  __syncthreads();
#pragma unroll 2
  for (int kb = 0; kb < 16; ++kb) {
    const int k = kb * 32 + kc * 8;
    s16x8 aF[2], bF[4];
#pragma unroll
    for (int mi = 0; mi < 2; ++mi) {
      int row = mi * 16 + arow;
      aF[mi] = *reinterpret_cast<const s16x8*>(&hA[(row << 10) + ((k * 2) ^ ((row & 7) << 4))]);
    }
#pragma unroll
    for (int ni = 0; ni < 4; ++ni) bF[ni] = *reinterpret_cast<const s16x8*>(bp[ni] + 512 + k);
#pragma unroll
    for (int mi = 0; mi < 2; ++mi)
#pragma unroll
      for (int ni = 0; ni < 4; ++ni)
        acc[mi][ni] = __builtin_amdgcn_mfma_f32_16x16x32_bf16(aF[mi], bF[ni], acc[mi][ni], 0, 0, 0);
  }
  __syncthreads();
#pragma unroll
  for (int mi = 0; mi < 2; ++mi)
#pragma unroll
    for (int q = 0; q < 4; ++q) {
      const int row = mi * 16 + kc * 4 + q;
#pragma unroll
      for (int ni = 0; ni < 4; ++ni) {
        const int col = colbase + ni * 16 + arow;
        float v = fmaxf(acc[mi][ni][q] + bov[ni], 0.f);
        *reinterpret_cast<u16*>(&hA[(row << 10) + ((col * 2) ^ ((row & 7) << 4))]) = f2b(v);
      }
    }
  __syncthreads();
  {
    char* dst = (char*)(hb + (size_t)m0 * DD);
#pragma unroll
    for (int c = tid; c < 2048; c += 512) {
      int row = c >> 6;
      int off = (c & 63) << 4;
      uint4 v = *reinterpret_cast<const uint4*>(&hA[(row << 10) + (off ^ ((row & 7) << 4))]);
      *reinterpret_cast<uint4*>(dst + (row << 10) + off) = v;
    }
  }
}

// classifier split-K partials: 16-way K split (512 blocks -> 2/CU)
__global__ __launch_bounds__(256) void k_cls(const u16* __restrict__ outb,
                                             const u16* __restrict__ wclsb,
                                             float* __restrict__ part) {
  const int tid = threadIdx.x, wid = tid >> 6, lane = tid & 63;
  const int rbase = blockIdx.x * 64 + wid * 16;
  const int ks = blockIdx.y;
  const int arow = lane & 15, kc = lane >> 4;
  f32x4 acc[4];
#pragma unroll
  for (int ni = 0; ni < 4; ++ni) acc[ni] = (f32x4){0.f, 0.f, 0.f, 0.f};
  const u16* ap = outb + (size_t)(rbase + arow) * KCLS;
  const int kbase = ks * (KCLS / 16);
#pragma unroll 2
  for (int kb = 0; kb < (KCLS / 16) / 32; ++kb) { // 53
    const int k = kbase + kb * 32 + kc * 8;
    s16x8 aF = *reinterpret_cast<const s16x8*>(ap + k);
#pragma unroll
    for (int ni = 0; ni < 4; ++ni) {
      s16x8 bF = *reinterpret_cast<const s16x8*>(wclsb + (size_t)(ni * 16 + arow) * KCLS + k);
      acc[ni] = __builtin_amdgcn_mfma_f32_16x16x32_bf16(aF, bF, acc[ni], 0, 0, 0);
    }
  }
#pragma unroll
  for (int ni = 0; ni < 4; ++ni)
#pragma unroll
    for (int q = 0; q < 4; ++q)
      part[(size_t)(ks * 2048 + rbase + kc * 4 + q) * 64 + ni * 16 + arow] = acc[ni][q];
}

__global__ void k_clsred(const float* __restrict__ part, const float* __restrict__ bcls,
                         float* __restrict__ outp) {
  int idx = blockIdx.x * 256 + threadIdx.x;
  if (idx >= RR * CCC) return;
  int r = idx / CCC;
  int c = idx - r * CCC;
  float s = bcls[c];
#pragma unroll
  for (int ks = 0; ks < 16; ++ks) s += part[(size_t)(ks * 2048 + r) * 64 + c];
  outp[idx] = s;
}

// ---------------- launcher ----------------

extern "C" void kernel_launch(void* const* d_in, const int* in_sizes, int n_in,
                              void* d_out, int out_size, void* d_ws, size_t ws_size,
                              hipStream_t stream) {
  (void)in_sizes; (void)n_in; (void)out_size;
  const int*   so     = (const int*)d_in[1];
  const float* inp    = (const float*)d_in[2];
  const float* matrix = (const float*)d_in[3];
  const float* w3w    = (const float*)d_in[4];
  const float* b3w    = (const float*)d_in[5];
  const float* w3u    = (const float*)d_in[6];
  const float* b3u    = (const float*)d_in[7];
  const float* w4w    = (const float*)d_in[8];
  const float* b4w    = (const float*)d_in[9];
  const float* w5w    = (const float*)d_in[10];
  const float* b5w    = (const float*)d_in[11];
  const float* w5u    = (const float*)d_in[12];
  const float* b5u    = (const float*)d_in[13];
  const float* wout   = (const float*)d_in[14];
  const float* bout   = (const float*)d_in[15];
  const float* wcls   = (const float*)d_in[16];
  const float* bcls   = (const float*)d_in[17];

  char* ws = (char*)d_ws;
  u16*   hb    = (u16*)  (ws + 0);          // 111,149,056
  float* Bmat  = (float*)(ws + 111149056);  // 417,792
  u16*   ar    = (u16*)  (ws + 111566848);  // 4,194,304
  u16*   gb    = (u16*)  (ws + 115761152);  // 12,589,056 (4098 rows)
  u16*   Wcat  = (u16*)  (ws + 128350208);  // 1,572,864
  u16*   w3ub  = (u16*)  (ws + 129923072);  // 524,288
  u16*   w5ub  = (u16*)  (ws + 130447360);  // 524,288
  u16*   woutb = (u16*)  (ws + 130971648);  // 1,048,576
  u16*   wclsb = (u16*)  (ws + 132020224);  // 3,473,408
  float* bias  = (float*)(ws + 135493632);  // 6,144
  // half-slice buffers (keeps g1->g2 working set L3-resident; full-M spilled L3)
  u16*   rvh_s = (u16*)  (ws + 139694080);  // 55,574,528
  unsigned char* zb8_s = (unsigned char*)(ws + 195268608); // 27,787,264 -> 223,055,872
  u16*   outb  = (u16*)  (ws + 139694080);  // reuses rvh region after GRU
  float* part  = (float*)(ws + 115761152);  // reuses gb (12.6MB >= 16*2048*64*4)
  const bool big = ws_size >= 250843136ULL;

  // prep (Bmat must precede k_redcvt)
  k_gatherB<<<dim3(2048), dim3(64), 0, stream>>>(so, matrix, Bmat);
  k_cvt4<<<dim3(256),   dim3(256), 0, stream>>>(w3u, w3ub, 65536);
  k_cvt4<<<dim3(256),   dim3(256), 0, stream>>>(w5u, w5ub, 65536);
  k_cvt4<<<dim3(512),   dim3(256), 0, stream>>>(wout, woutb, 131072);
  k_wcls<<<dim3(64),    dim3(256), 0, stream>>>(wcls, wclsb);
  k_wcat<<<dim3(3072),  dim3(256), 0, stream>>>(w3w, w4w, w5w, Wcat);
  k_bias<<<dim3(2), dim3(256), 0, stream>>>(b3w, b3u, b4w, b5w, b5u, bias);

  // 3 GRU time steps
  for (int t = 0; t < 3; ++t) {
    if (t == 0)
      k_redcvt<<<dim3(2048), dim3(256), 0, stream>>>(inp, Bmat, hb, ar);
    else
      k_reduce<<<dim3(2048), dim3(256), 0, stream>>>(hb, Bmat, ar);
    k_agemm<<<dim3(64, 24), dim3(256), 0, stream>>>(ar, Wcat, gb);
    if (big) {
      k_g1<<<dim3(1696), dim3(512), 0, stream>>>(hb, w3ub, gb, Bmat, bias, rvh_s, zb8_s, 0);
      k_g2<<<dim3(1696), dim3(512), 0, stream>>>(hb, w5ub, gb, Bmat, bias, rvh_s, zb8_s, 0);
      k_g1<<<dim3(1696), dim3(512), 0, stream>>>(hb, w3ub, gb, Bmat, bias, rvh_s, zb8_s, MHALF);
      k_g2<<<dim3(1696), dim3(512), 0, stream>>>(hb, w5ub, gb, Bmat, bias, rvh_s, zb8_s, MHALF);
    } else {
      k_gru<<<dim3(3392), dim3(512), 0, stream>>>(hb, w3ub, w5ub, gb, Bmat, bias);
    }
  }

  // output projection + classifier
  if (big) {
    k_out2<<<dim3(3392), dim3(512), 0, stream>>>(hb, inp, woutb, bout, outb);
    k_cls<<<dim3(32, 16), dim3(256), 0, stream>>>(outb, wclsb, part);
  } else {
    k_out<<<dim3(3392), dim3(512), 0, stream>>>(hb, inp, woutb, bout);
    k_cls<<<dim3(32, 16), dim3(256), 0, stream>>>(hb, wclsb, part);
  }
  k_clsred<<<dim3(408), dim3(256), 0, stream>>>(part, bcls, (float*)d_out);
}